// Round 3
// baseline (245.019 us; speedup 1.0000x reference)
//
#include <hip/hip_runtime.h>

#define Bn 16
#define Cn 64
#define Hn 128
#define Wn 128
#define HWn (Hn * Wn)

// ---------------------------------------------------------------------------
// Single fused kernel:
//   prelude (per block, redundant per batch):
//     hid  = lrelu(d[b] @ Wk1^T)            (64)     -> LDS
//     kern = hid @ Wk2^T                    (576)    -> LDS (rows padded to 12)
//   main loop (per output pixel):
//     dynamic depthwise 3x3 (SAME) -> lrelu -> 1x1 conv (Wc) + bias
//
// Why fused: any small-grid gen kernel is latency-bound (R2: 85us at 0.2%
// VALUBusy). Redundant per-block recompute is ~42M FMA total, hidden by TLP.
//
// kern taps read from LDS as wave-uniform float4 broadcasts; Wc[o*64+c] and
// bc[o] are wave-uniform -> scalar-pipe loads (K$, 16KB = whole Wc).
// Border masks applied once at tap load, not per-channel.
// Block = 256 threads = 64(w) x 4(h). Grid = (2, 32, 16) = 1024 blocks.
// ---------------------------------------------------------------------------
__global__ __launch_bounds__(256, 4)
void da_fused(const float* __restrict__ x,
              const float* __restrict__ dvec,
              const float* __restrict__ Wk1,
              const float* __restrict__ Wk2,
              const float* __restrict__ Wc,
              const float* __restrict__ bc,
              float* __restrict__ out) {
    const int t = threadIdx.x;
    const int w = (blockIdx.x << 6) + (t & 63);
    const int h = (blockIdx.y << 2) + (t >> 6);
    const int b = blockIdx.z;

    __shared__ float  hid_s[64];
    __shared__ float4 kern4[64 * 3];           // 64 rows x 12 floats (9 used)
    float* const kern_sf = (float*)kern4;

    // ---- tap offsets + masks (per-thread, once) ----
    int rofs[3]; bool rok[3];
    int cofs[3]; bool cok[3];
    #pragma unroll
    for (int i = 0; i < 3; ++i) {
        const int hh = h + i - 1;
        rok[i]  = (hh >= 0) && (hh < Hn);
        rofs[i] = (hh < 0 ? 0 : (hh >= Hn ? Hn - 1 : hh)) * Wn;
        const int ww = w + i - 1;
        cok[i]  = (ww >= 0) && (ww < Wn);
        cofs[i] = (ww < 0 ? 0 : (ww >= Wn - 1 ? Wn - 1 : ww));
    }
    int  off[9];
    bool msk[9];
    #pragma unroll
    for (int r = 0; r < 3; ++r)
        #pragma unroll
        for (int c2 = 0; c2 < 3; ++c2) {
            off[r * 3 + c2] = rofs[r] + cofs[c2];
            msk[r * 3 + c2] = rok[r] && cok[c2];
        }

    const float* __restrict__ xb = x + (size_t)b * Cn * HWn;

    // Issue channel-0 tap loads early; they stay in flight across the prelude.
    float cur[9];
    #pragma unroll
    for (int i = 0; i < 9; ++i) cur[i] = msk[i] ? xb[off[i]] : 0.f;

    // ---- prelude: hid (threads 0..63), then kern (all threads) ----
    if (t < 64) {
        const float* __restrict__ wr = Wk1 + t * 64;
        const float* __restrict__ db = dvec + b * 64;   // uniform -> s_load
        float s0 = 0.f, s1 = 0.f, s2 = 0.f, s3 = 0.f;
        #pragma unroll
        for (int j = 0; j < 64; j += 4) {
            s0 += db[j + 0] * wr[j + 0];
            s1 += db[j + 1] * wr[j + 1];
            s2 += db[j + 2] * wr[j + 2];
            s3 += db[j + 3] * wr[j + 3];
        }
        const float s = (s0 + s1) + (s2 + s3);
        hid_s[t] = (s >= 0.f) ? s : 0.1f * s;
    }
    __syncthreads();

    {
        // zero the pad lanes once (avoid reading 0xAA via float4 tails)
        for (int o = t; o < 576; o += 256) {
            const float* __restrict__ wr = Wk2 + o * 64;
            float s0 = 0.f, s1 = 0.f, s2 = 0.f, s3 = 0.f;
            #pragma unroll
            for (int j = 0; j < 64; j += 4) {
                s0 += hid_s[j + 0] * wr[j + 0];
                s1 += hid_s[j + 1] * wr[j + 1];
                s2 += hid_s[j + 2] * wr[j + 2];
                s3 += hid_s[j + 3] * wr[j + 3];
            }
            const int c = o / 9, tap = o - c * 9;
            kern_sf[c * 12 + tap] = (s0 + s1) + (s2 + s3);
        }
    }
    __syncthreads();

    // ---- main loop ----
    float acc[64];
    #pragma unroll
    for (int o = 0; o < 64; ++o) acc[o] = bc[o];       // uniform -> s_load

    #pragma unroll 2
    for (int c = 0; c < Cn; ++c) {
        // prefetch next channel's taps while this channel's FMAs run
        const float* __restrict__ xn = xb + (c + 1 < Cn ? c + 1 : c) * HWn;
        float nxt[9];
        #pragma unroll
        for (int i = 0; i < 9; ++i) nxt[i] = msk[i] ? xn[off[i]] : 0.f;

        // kern row c: wave-uniform float4 broadcast from LDS
        const float4 ka = kern4[c * 3 + 0];
        const float4 kb = kern4[c * 3 + 1];
        const float  k8 = kern_sf[c * 12 + 8];

        float v = cur[0] * ka.x + cur[1] * ka.y + cur[2] * ka.z +
                  cur[3] * ka.w + cur[4] * kb.x + cur[5] * kb.y +
                  cur[6] * kb.z + cur[7] * kb.w + cur[8] * k8;
        v = (v >= 0.f) ? v : 0.1f * v;

        // 1x1 conv: Wc[o*64+c] wave-uniform -> scalar loads (K$-resident)
        const float* __restrict__ wc_c = Wc + c;
        #pragma unroll
        for (int o = 0; o < 64; ++o)
            acc[o] += v * wc_c[(size_t)o * 64];

        #pragma unroll
        for (int i = 0; i < 9; ++i) cur[i] = nxt[i];
    }

    float* __restrict__ ob = out + (size_t)b * Cn * HWn + h * Wn + w;
    #pragma unroll
    for (int o = 0; o < 64; ++o)
        ob[(size_t)o * HWn] = acc[o];
}

// ---------------------------------------------------------------------------
extern "C" void kernel_launch(void* const* d_in, const int* in_sizes, int n_in,
                              void* d_out, int out_size, void* d_ws, size_t ws_size,
                              hipStream_t stream) {
    const float* x   = (const float*)d_in[0];
    const float* d   = (const float*)d_in[1];
    const float* Wk1 = (const float*)d_in[2];
    const float* Wk2 = (const float*)d_in[3];
    const float* Wc  = (const float*)d_in[4];
    const float* bc  = (const float*)d_in[5];
    float* out = (float*)d_out;

    da_fused<<<dim3(Wn / 64, Hn / 4, Bn), dim3(256), 0, stream>>>(
        x, d, Wk1, Wk2, Wc, bc, out);
}

// Round 4
// 170.028 us; speedup vs baseline: 1.4411x; 1.4411x over previous
//
#include <hip/hip_runtime.h>

#define Bn 16
#define Cn 64
#define Hn 128
#define Wn 128
#define HWn (Hn * Wn)

// CK-style raw buffer load: OOB offsets (voffset+4 > num_records) return 0.0f.
using int32x4 = int __attribute__((ext_vector_type(4)));
__device__ float
llvm_amdgcn_raw_buffer_load_fp32(int32x4 srsrc, int voffset, int soffset,
                                 int glc_slc) __asm("llvm.amdgcn.raw.buffer.load.f32");

__device__ __forceinline__ int32x4 make_rsrc(const void* p) {
    int32x4 r;
    r.x = (int)(unsigned)(uintptr_t)p;
    r.y = (int)((uintptr_t)p >> 32);   // stride=0 in [29:16]
    r.z = HWn * 4;                      // num_records (bytes)
    r.w = 0x00020000;                   // raw dword SRD
    return r;
}

__device__ __forceinline__ float wave_reduce64(float v) {
    #pragma unroll
    for (int m = 1; m < 64; m <<= 1) v += __shfl_xor(v, m, 64);
    return v;
}

// ---------------------------------------------------------------------------
// Kernel-gen, wide grid: block (b, r) computes kern[b, r*64 .. r*64+63].
// 144 blocks x 4 waves -> enough TLP to hide the shfl chains (R2: 16 blocks
// was 85us at 0.2% VALUBusy; same math on 9x the blocks).
// Lane j reads element j of each weight row (coalesced), shfl-reduce.
// Block (0,0) additionally transposes Wc -> WcT (coalesced writes).
// ---------------------------------------------------------------------------
__global__ __launch_bounds__(256)
void gen_kern3(const float* __restrict__ d,
               const float* __restrict__ Wk1,
               const float* __restrict__ Wk2,
               const float* __restrict__ Wc,
               float* __restrict__ kern_out,   // ws: [16][576]
               float* __restrict__ WcT) {      // ws: [64][64], WcT[c][o]
    const int b    = blockIdx.x;        // 16
    const int r    = blockIdx.y;        // 9
    const int lane = threadIdx.x & 63;
    const int wv   = threadIdx.x >> 6;  // 0..3
    __shared__ float hid_s[64];

    const float dj = d[b * 64 + lane];

    #pragma unroll
    for (int i = 0; i < 16; ++i) {          // hid: 64 outputs over 4 waves
        const int o = wv * 16 + i;
        float p = wave_reduce64(Wk1[o * 64 + lane] * dj);
        if (lane == 0) hid_s[o] = (p >= 0.f) ? p : 0.1f * p;
    }
    __syncthreads();
    const float hj = hid_s[lane];

    #pragma unroll
    for (int i = 0; i < 16; ++i) {          // this block's 64 kern outputs
        const int o = r * 64 + wv * 16 + i;
        float p = wave_reduce64(Wk2[o * 64 + lane] * hj);
        if (lane == 0) kern_out[b * 576 + o] = p;
    }

    if (b == 0 && r == 0) {                 // WcT[c*64+o] = Wc[o*64+c]
        for (int idx = threadIdx.x; idx < 4096; idx += 256)
            WcT[idx] = Wc[(idx & 63) * 64 + (idx >> 6)];
    }
}

// ---------------------------------------------------------------------------
// Main fused conv. One thread per output pixel; acc[64] lives in AGPRs
// (unified file). No LDS. Depth-2 software pipeline over channels with
// triple tap-buffers: load c+2 while computing c (load->use distance
// ~2 iterations > L2 latency). Border taps return 0 via buffer OOB
// (sentinel byte offsets >= 0x10000000) -- zero VALU masking cost.
// kern row (s_load from ws) and WcT row (s_load_dwordx16) are wave-uniform.
// ---------------------------------------------------------------------------
__global__ __launch_bounds__(256, 4)
void da_main(const float* __restrict__ x,
             const float* __restrict__ kern,
             const float* __restrict__ WcT,
             const float* __restrict__ bc,
             float* __restrict__ out) {
    const int w = (blockIdx.x << 6) + (threadIdx.x & 63);
    const int h = (blockIdx.y << 2) + (threadIdx.x >> 6);
    const int b = blockIdx.z;

    const float* __restrict__ xb = x + (size_t)b * Cn * HWn;
    const float* __restrict__ kb = kern + b * 576;

    // Byte tap offsets; invalid row/col -> sentinel (OOB in 64KB SRD, no
    // 32-bit wrap: max 0x20000200).
    int rofsB[3], cofsB[3];
    #pragma unroll
    for (int i = 0; i < 3; ++i) {
        const int hh = h + i - 1;
        rofsB[i] = (hh >= 0 && hh < Hn) ? hh * (Wn * 4) : 0x10000000;
        const int ww = w + i - 1;
        cofsB[i] = (ww >= 0 && ww < Wn) ? ww * 4 : 0x10000000;
    }
    int voff[9];
    #pragma unroll
    for (int r = 0; r < 3; ++r)
        #pragma unroll
        for (int c2 = 0; c2 < 3; ++c2)
            voff[r * 3 + c2] = rofsB[r] + cofsB[c2];

    float acc[64];
    #pragma unroll
    for (int o = 0; o < 64; ++o) acc[o] = bc[o];

    float A[9], B[9], C[9];

    // preload channels 0,1
    {
        int32x4 r0 = make_rsrc(xb);
        int32x4 r1 = make_rsrc(xb + HWn);
        #pragma unroll
        for (int i = 0; i < 9; ++i) A[i] = llvm_amdgcn_raw_buffer_load_fp32(r0, voff[i], 0, 0);
        #pragma unroll
        for (int i = 0; i < 9; ++i) B[i] = llvm_amdgcn_raw_buffer_load_fp32(r1, voff[i], 0, 0);
    }

#define STEP(cc, BU, BL) {                                                     \
        const int _cl = ((cc) + 2 < Cn) ? (cc) + 2 : Cn - 1;                   \
        const int32x4 _rs = make_rsrc(xb + _cl * HWn);                         \
        _Pragma("unroll")                                                      \
        for (int i = 0; i < 9; ++i)                                            \
            BL[i] = llvm_amdgcn_raw_buffer_load_fp32(_rs, voff[i], 0, 0);      \
        const float* __restrict__ kr = kb + (cc) * 9;                          \
        float v = BU[0]*kr[0] + BU[1]*kr[1] + BU[2]*kr[2]                      \
                + BU[3]*kr[3] + BU[4]*kr[4] + BU[5]*kr[5]                      \
                + BU[6]*kr[6] + BU[7]*kr[7] + BU[8]*kr[8];                     \
        v = (v >= 0.f) ? v : 0.1f * v;                                         \
        const float* __restrict__ wcc = WcT + ((cc) << 6);                     \
        _Pragma("unroll")                                                      \
        for (int o = 0; o < 64; ++o) acc[o] += v * wcc[o];                     \
    }

    for (int c = 0; c < 63; c += 3) {   // 21 triples: channels 0..62
        STEP(c + 0, A, C);
        STEP(c + 1, B, A);
        STEP(c + 2, C, B);
    }
    STEP(63, A, C);                     // epilogue (redundant prefetch, harmless)
#undef STEP

    float* __restrict__ ob = out + (size_t)b * Cn * HWn + h * Wn + w;
    #pragma unroll
    for (int o = 0; o < 64; ++o)
        ob[(size_t)o * HWn] = acc[o];
}

// ---------------------------------------------------------------------------
extern "C" void kernel_launch(void* const* d_in, const int* in_sizes, int n_in,
                              void* d_out, int out_size, void* d_ws, size_t ws_size,
                              hipStream_t stream) {
    const float* x   = (const float*)d_in[0];
    const float* d   = (const float*)d_in[1];
    const float* Wk1 = (const float*)d_in[2];
    const float* Wk2 = (const float*)d_in[3];
    const float* Wc  = (const float*)d_in[4];
    const float* bc  = (const float*)d_in[5];
    float* out  = (float*)d_out;
    float* kern = (float*)d_ws;                 // 16*576 floats
    float* WcT  = (float*)d_ws + Bn * 576;      // 64*64 floats

    gen_kern3<<<dim3(Bn, 9), dim3(256), 0, stream>>>(d, Wk1, Wk2, Wc, kern, WcT);
    da_main<<<dim3(Wn / 64, Hn / 4, Bn), dim3(256), 0, stream>>>(x, kern, WcT, bc, out);
}

// Round 5
// 164.949 us; speedup vs baseline: 1.4854x; 1.0308x over previous
//
#include <hip/hip_runtime.h>

#define Bn 16
#define Cn 64
#define Hn 128
#define Wn 128
#define HWn (Hn * Wn)

// Raw buffer load: OOB offsets (voffset+4 > num_records) return 0.0f.
using int32x4 = int __attribute__((ext_vector_type(4)));
__device__ float
llvm_amdgcn_raw_buffer_load_fp32(int32x4 srsrc, int voffset, int soffset,
                                 int glc_slc) __asm("llvm.amdgcn.raw.buffer.load.f32");

__device__ __forceinline__ int32x4 make_rsrc(const void* p) {
    int32x4 r;
    r.x = (int)(unsigned)(uintptr_t)p;
    r.y = (int)((uintptr_t)p >> 32);   // stride=0
    r.z = HWn * 4;                      // num_records (bytes)
    r.w = 0x00020000;                   // raw dword SRD
    return r;
}

// ---------------------------------------------------------------------------
// Kernel-gen, NO shfl (R2/R4 lesson: shfl chains are latency-doomed).
// Grid (16,3) x 192 threads. Thread t of block (b,r) computes
// kern[b, r*192+t] as a direct dot-64 with 4 partial sums (float4 loads).
// hid computed redundantly per block by threads 0..63. Block (0,0) also
// transposes Wc -> WcT.
// ---------------------------------------------------------------------------
__global__ __launch_bounds__(192)
void gen_kern4(const float* __restrict__ d,
               const float* __restrict__ Wk1,
               const float* __restrict__ Wk2,
               const float* __restrict__ Wc,
               float* __restrict__ kern_out,   // ws: [16][576]
               float* __restrict__ WcT) {      // ws: [64][64], WcT[c][o]
    const int b = blockIdx.x;   // 16
    const int r = blockIdx.y;   // 3
    const int t = threadIdx.x;  // 192
    __shared__ float hid_s[64];

    if (t < 64) {
        const float4* __restrict__ w4 = (const float4*)(Wk1 + (size_t)t * 64);
        const float*  __restrict__ db = d + b * 64;        // uniform -> s_load
        float s0 = 0.f, s1 = 0.f, s2 = 0.f, s3 = 0.f;
        #pragma unroll
        for (int j = 0; j < 16; ++j) {
            const float4 wv = w4[j];
            s0 += db[4 * j + 0] * wv.x;
            s1 += db[4 * j + 1] * wv.y;
            s2 += db[4 * j + 2] * wv.z;
            s3 += db[4 * j + 3] * wv.w;
        }
        const float s = (s0 + s1) + (s2 + s3);
        hid_s[t] = (s >= 0.f) ? s : 0.1f * s;
    }
    __syncthreads();

    {
        const int o = r * 192 + t;                         // 576 = 3*192
        const float4* __restrict__ w4 = (const float4*)(Wk2 + (size_t)o * 64);
        const float4* __restrict__ h4 = (const float4*)hid_s;
        float s0 = 0.f, s1 = 0.f, s2 = 0.f, s3 = 0.f;
        #pragma unroll
        for (int j = 0; j < 16; ++j) {
            const float4 wv = w4[j];
            const float4 hv = h4[j];
            s0 += hv.x * wv.x;
            s1 += hv.y * wv.y;
            s2 += hv.z * wv.z;
            s3 += hv.w * wv.w;
        }
        kern_out[b * 576 + o] = (s0 + s1) + (s2 + s3);
    }

    if (b == 0 && r == 0) {                                // WcT[c*64+o]=Wc[o*64+c]
        for (int idx = t; idx < 4096; idx += 192)
            WcT[idx] = Wc[(idx & 63) * 64 + (idx >> 6)];
    }
}

// ---------------------------------------------------------------------------
// Main fused conv. Each thread: 2 vertical pixels (h0,h0+1) x 32 output
// channels (osel = wave-uniform t>>7, scalarized via readfirstlane so the
// WcT/bc reads stay on the scalar pipe). Vertical pair shares tap rows:
// 12 buffer loads feed both pixels' 9-tap stencils (two independent FMA
// chains). Triple-buffered depth-2 channel pipeline; borders via buffer-OOB
// sentinel offsets (HW returns 0, zero VALU masking).
// Block 256 = 64(w) x 2(hpair) x 2(osel); grid (2,32,16) = 1024 blocks.
// ---------------------------------------------------------------------------
__global__ __launch_bounds__(256, 4)
void da_main(const float* __restrict__ x,
             const float* __restrict__ kern,
             const float* __restrict__ WcT,
             const float* __restrict__ bc,
             float* __restrict__ out) {
    const int t     = threadIdx.x;
    const int wlane = t & 63;
    const int hg    = (t >> 6) & 1;
    const int w  = (blockIdx.x << 6) + wlane;
    const int h0 = (blockIdx.y << 2) + (hg << 1);    // rows h0, h0+1
    const int b  = blockIdx.z;
    const int obase = __builtin_amdgcn_readfirstlane((t >> 7) << 5); // 0 or 32

    const float* __restrict__ xb = x + (size_t)b * Cn * HWn;
    const float* __restrict__ kb = kern + b * 576;

    // 4 tap rows (h0-1..h0+2) x 3 cols; invalid -> OOB sentinel
    int rofsB[4], cofsB[3];
    #pragma unroll
    for (int i = 0; i < 4; ++i) {
        const int hh = h0 - 1 + i;
        rofsB[i] = (hh >= 0 && hh < Hn) ? hh * (Wn * 4) : 0x10000000;
    }
    #pragma unroll
    for (int i = 0; i < 3; ++i) {
        const int ww = w - 1 + i;
        cofsB[i] = (ww >= 0 && ww < Wn) ? ww * 4 : 0x10000000;
    }
    int voff[12];
    #pragma unroll
    for (int r = 0; r < 4; ++r)
        #pragma unroll
        for (int c2 = 0; c2 < 3; ++c2)
            voff[r * 3 + c2] = rofsB[r] + cofsB[c2];

    float acc0[32], acc1[32];
    const float* __restrict__ bcp = bc + obase;          // uniform -> s_load
    #pragma unroll
    for (int o = 0; o < 32; ++o) { acc0[o] = bcp[o]; acc1[o] = bcp[o]; }

    float A[12], B[12], C[12];
    {
        const int32x4 r0 = make_rsrc(xb);
        const int32x4 r1 = make_rsrc(xb + HWn);
        #pragma unroll
        for (int i = 0; i < 12; ++i) A[i] = llvm_amdgcn_raw_buffer_load_fp32(r0, voff[i], 0, 0);
        #pragma unroll
        for (int i = 0; i < 12; ++i) B[i] = llvm_amdgcn_raw_buffer_load_fp32(r1, voff[i], 0, 0);
    }

#define STEP(cc, U, L) {                                                       \
        const int _cl = ((cc) + 2 < Cn) ? (cc) + 2 : Cn - 1;                   \
        const int32x4 _rs = make_rsrc(xb + _cl * HWn);                         \
        _Pragma("unroll")                                                      \
        for (int i = 0; i < 12; ++i)                                           \
            L[i] = llvm_amdgcn_raw_buffer_load_fp32(_rs, voff[i], 0, 0);       \
        const float* __restrict__ kr = kb + (cc) * 9;                          \
        float v0 = U[0]*kr[0] + U[1]*kr[1] + U[2]*kr[2]                        \
                 + U[3]*kr[3] + U[4]*kr[4] + U[5]*kr[5]                        \
                 + U[6]*kr[6] + U[7]*kr[7] + U[8]*kr[8];                       \
        float v1 = U[3]*kr[0] + U[4]*kr[1] + U[5]*kr[2]                        \
                 + U[6]*kr[3] + U[7]*kr[4] + U[8]*kr[5]                        \
                 + U[9]*kr[6] + U[10]*kr[7] + U[11]*kr[8];                     \
        v0 = (v0 >= 0.f) ? v0 : 0.1f * v0;                                     \
        v1 = (v1 >= 0.f) ? v1 : 0.1f * v1;                                     \
        const float* __restrict__ wcc = WcT + ((cc) << 6) + obase;             \
        _Pragma("unroll")                                                      \
        for (int o = 0; o < 32; ++o) {                                         \
            acc0[o] += v0 * wcc[o];                                            \
            acc1[o] += v1 * wcc[o];                                            \
        }                                                                      \
    }

    for (int c = 0; c < 63; c += 3) {   // 21 triples: channels 0..62
        STEP(c + 0, A, C);
        STEP(c + 1, B, A);
        STEP(c + 2, C, B);
    }
    STEP(63, A, C);                     // epilogue (redundant prefetch)
#undef STEP

    float* __restrict__ ob = out + (size_t)b * Cn * HWn
                           + (size_t)obase * HWn + h0 * Wn + w;
    #pragma unroll
    for (int o = 0; o < 32; ++o) {
        ob[(size_t)o * HWn]      = acc0[o];
        ob[(size_t)o * HWn + Wn] = acc1[o];
    }
}

// ---------------------------------------------------------------------------
extern "C" void kernel_launch(void* const* d_in, const int* in_sizes, int n_in,
                              void* d_out, int out_size, void* d_ws, size_t ws_size,
                              hipStream_t stream) {
    const float* x   = (const float*)d_in[0];
    const float* d   = (const float*)d_in[1];
    const float* Wk1 = (const float*)d_in[2];
    const float* Wk2 = (const float*)d_in[3];
    const float* Wc  = (const float*)d_in[4];
    const float* bc  = (const float*)d_in[5];
    float* out  = (float*)d_out;
    float* kern = (float*)d_ws;                 // 16*576 floats
    float* WcT  = (float*)d_ws + Bn * 576;      // 64*64 floats

    gen_kern4<<<dim3(Bn, 3), dim3(192), 0, stream>>>(d, Wk1, Wk2, Wc, kern, WcT);
    da_main<<<dim3(Wn / 64, Hn / 4, Bn), dim3(256), 0, stream>>>(x, kern, WcT, bc, out);
}